// Round 22
// baseline (81.161 us; speedup 1.0000x reference)
//
#include <hip/hip_runtime.h>
#include <hip/hip_bf16.h>

#define NROW 8192
#define NDIM 128
#define CTILE 32   // cols per tile; dbuf 2x8KB=16KB LDS -> ~10 single-wave blocks/CU
#define NTILE 16   // tiles per block -> 512 cols/block
#define RWAVE 64   // rows per wave;  grid (16,128) = 2048 one-wave blocks
#define CAP 64     // max rows per class (mean 16, P(>64) ~ 1e-20, guarded)
#define NCLS 512

typedef __attribute__((ext_vector_type(8))) short short8;
typedef __attribute__((ext_vector_type(4))) float f32x4;
typedef __attribute__((address_space(1))) const unsigned int guint;
typedef __attribute__((address_space(3))) unsigned int luint;

__device__ __forceinline__ unsigned f2u_mono(float f) {
  unsigned u = __float_as_uint(f);
  return (u & 0x80000000u) ? ~u : (u | 0x80000000u);
}
__device__ __forceinline__ float u2f_mono(unsigned u) {
  return __uint_as_float((u & 0x80000000u) ? (u ^ 0x80000000u) : ~u);
}
__device__ __forceinline__ unsigned short f2bf(float f) {  // RTN fp32->bf16
  unsigned u = __float_as_uint(f);
  u += 0x7fffu + ((u >> 16) & 1u);
  return (unsigned short)(u >> 16);
}

// ONE prologue kernel (512 blocks): zero-init + bf16 convert + per-class
// positive pairs (discovery by label scan, LDS-staged fp32 dots, pcache).
__global__ __launch_bounds__(256) void k_pre(
    const float* __restrict__ emb, const int* __restrict__ labels,
    unsigned short* __restrict__ h,
    unsigned* __restrict__ nmaxu, float* __restrict__ anb, float* __restrict__ hnb,
    float* __restrict__ pmin, float* __restrict__ apb, int* __restrict__ rcnt,
    float* __restrict__ pcache, unsigned* __restrict__ done_partial) {
  __shared__ float Le[CAP][NDIM + 1];  // +1 pad: bank (j+d)%32 -> conflict-free
  __shared__ int rows_s[CAP];
  __shared__ int scnt;

  const int t = threadIdx.x;
  const int c = blockIdx.x;
  const int gid = c * 256 + t;

  if (gid < NROW) {
    nmaxu[gid] = 0u;   // mono sentinel: decodes to NaN -> compares false
    anb[gid] = 0.f;
    hnb[gid] = 0.f;
  }
  if (c == 0 && t < 3) done_partial[t] = 0u;  // done, partial[0..1]

  {  // bf16 convert slab
    int i = gid * 8;
    float4 f0 = *reinterpret_cast<const float4*>(emb + i);
    float4 f1 = *reinterpret_cast<const float4*>(emb + i + 4);
    ushort4 a, b;
    a.x = f2bf(f0.x); a.y = f2bf(f0.y); a.z = f2bf(f0.z); a.w = f2bf(f0.w);
    b.x = f2bf(f1.x); b.y = f2bf(f1.y); b.z = f2bf(f1.z); b.w = f2bf(f1.w);
    *reinterpret_cast<ushort4*>(h + i) = a;
    *reinterpret_cast<ushort4*>(h + i + 4) = b;
  }

  if (t == 0) scnt = 0;
  __syncthreads();
#pragma unroll
  for (int it = 0; it < NROW / 256; ++it) {
    const int row = it * 256 + t;
    if (labels[row] == c) {
      const int idx = atomicAdd(&scnt, 1);
      if (idx < CAP) rows_s[idx] = row;
    }
  }
  __syncthreads();
  const int cnt = min(scnt, CAP);
  if (cnt == 0) return;  // class absent (block-uniform)

  for (int idx = t; idx < cnt * NDIM; idx += 256) {
    const int k = idx >> 7, d = idx & 127;
    Le[k][d] = emb[(size_t)rows_s[k] * NDIM + d];
  }
  __syncthreads();

  const int il = t >> 4, jl = t & 15;
  for (int ib = 0; ib < cnt; ib += 16) {
    const int i = ib + il;
    float pm = INFINITY, apv = 0.f;
    for (int jb = 0; jb < cnt; jb += 16) {
      const int j = jb + jl;
      float p = INFINITY;
      if (i < cnt && j < cnt) {
        if (i != j) {
          float s = 0.f;
#pragma unroll 8
          for (int d = 0; d < NDIM; ++d) s = fmaf(Le[i][d], Le[j][d], s);
          p = s;
        }
        pcache[(size_t)rows_s[i] * CAP + j] = p;  // +INF on diagonal
        if (i != j) {
          pm = fminf(pm, p);
          apv += exp2f(fmaf(p, -2.885390082f, 1.442695041f));  // exp(-2(p-.5))
        }
      }
    }
    pm = fminf(pm, __shfl_xor(pm, 1)); pm = fminf(pm, __shfl_xor(pm, 2));
    pm = fminf(pm, __shfl_xor(pm, 4)); pm = fminf(pm, __shfl_xor(pm, 8));
    apv += __shfl_xor(apv, 1); apv += __shfl_xor(apv, 2);
    apv += __shfl_xor(apv, 4); apv += __shfl_xor(apv, 8);
    if (jl == 0 && i < cnt) {
      pmin[rows_s[i]] = pm;   // +INF if class has a single row
      apb[rows_s[i]] = apv;
      rcnt[rows_s[i]] = cnt;
    }
  }
}

// Stage one 32x128 bf16 col-tile into this wave's private LDS buffer (8 DMA).
// Dest LINEAR (base + lane*16); XOR swizzle on the GLOBAL source chunk.
__device__ __forceinline__ void stage_tile(const unsigned short* __restrict__ eh,
                                           int colBase, int t,
                                           unsigned short* __restrict__ Lbuf) {
#pragma unroll
  for (int it = 0; it < 8; ++it) {
    const int idx = it * 64 + t;
    const int r = idx >> 4;             // 0..31
    const int c = idx & 15;
    const int q = c ^ (r & 15);
    const unsigned short* src = eh + (size_t)(colBase + r) * NDIM + q * 8;
    unsigned short* dst = Lbuf + r * NDIM + c * 8;
    __builtin_amdgcn_global_load_lds((guint*)src, (luint*)dst, 16, 0, 0);
  }
}

// Barrier-free negatives GEMM: ONE WAVE per block (no __syncthreads anywhere).
// Private LDS double-buffer + counted per-wave vmcnt: stage(t+1) stays in
// flight across the whole tile-compute (never drain to 0 mid-loop, T4).
// x-trick epilogue: x = eq ? -inf : s feeds nmax/exp/compare uniformly.
__global__ __launch_bounds__(64) void k_neg(
    const unsigned short* __restrict__ eh, const int* __restrict__ labels,
    const float* __restrict__ pmin, unsigned* __restrict__ nmaxu,
    float* __restrict__ anb, float* __restrict__ hnb) {
  __shared__ unsigned short L[2][CTILE * NDIM];  // 2 x 8KB, private to the wave

  const int t = threadIdx.x;          // lane 0..63
  const int g = t >> 4;
  const int l15 = t & 15;
  const int rowBase = blockIdx.y * RWAVE;
  const int col0 = blockIdx.x * NTILE * CTILE;

  // row fragments (64 rows), labels, thresholds — then drain so loop counts are exact
  short8 bv[4][4];  // [kk][n]
  int lr[4];
  float thrn[4];
#pragma unroll
  for (int n = 0; n < 4; ++n) {
    const int grow = rowBase + n * 16 + l15;
    lr[n] = labels[grow];
    thrn[n] = pmin[grow] - 0.1f;  // +INF if no positives -> x>thrn false -> hn=0
#pragma unroll
    for (int kk = 0; kk < 4; ++kk)
      bv[kk][n] = *reinterpret_cast<const short8*>(eh + (size_t)grow * NDIM + kk * 32 + g * 8);
  }
  asm volatile("s_waitcnt vmcnt(0)" ::: "memory");  // prologue drain

  stage_tile(eh, col0, t, L[0]);  // tile 0 DMA (8 outstanding)

  float nmaxA[4] = {-INFINITY, -INFINITY, -INFINITY, -INFINITY};
  float anA[4] = {0.f, 0.f, 0.f, 0.f}, hnA[4] = {0.f, 0.f, 0.f, 0.f};
  const f32x4 Z = {0.f, 0.f, 0.f, 0.f};

  int cur = 0;
  for (int tt = 0; tt < NTILE; ++tt) {
    const int colBase = col0 + tt * CTILE;
    const bool more = (tt + 1 < NTILE);
    if (more) stage_tile(eh, colBase + CTILE, t, L[cur ^ 1]);  // +8 DMA
    int4 lcv[2];                                               // +2 VMEM
#pragma unroll
    for (int m = 0; m < 2; ++m)
      lcv[m] = *reinterpret_cast<const int4*>(labels + colBase + m * 16 + g * 4);
    // wait: cur-tile DMA done; next-tile 8 DMA + 2 lcv still in flight
    if (more) asm volatile("s_waitcnt vmcnt(10)" ::: "memory");
    else      asm volatile("s_waitcnt vmcnt(2)" ::: "memory");
    __builtin_amdgcn_sched_barrier(0);

    f32x4 acc[2][4];
    __builtin_amdgcn_s_setprio(1);
#pragma unroll
    for (int kk = 0; kk < 4; ++kk) {
      short8 av[2];
#pragma unroll
      for (int m = 0; m < 2; ++m) {
        const int R = m * 16 + l15;
        const int pc = (kk * 4 + g) ^ l15;
        av[m] = *reinterpret_cast<const short8*>(L[cur] + R * NDIM + pc * 8);
      }
#pragma unroll
      for (int m = 0; m < 2; ++m)
#pragma unroll
        for (int n = 0; n < 4; ++n)
          acc[m][n] = __builtin_amdgcn_mfma_f32_16x16x32_bf16(
              av[m], bv[kk][n], (kk == 0) ? Z : acc[m][n], 0, 0, 0);
    }
    __builtin_amdgcn_s_setprio(0);

    // wait: lcv landed (covered by MFMA); next-tile 8 DMA still in flight
    if (more) asm volatile("s_waitcnt vmcnt(8)" ::: "memory");
    else      asm volatile("s_waitcnt vmcnt(0)" ::: "memory");
    __builtin_amdgcn_sched_barrier(0);

#pragma unroll
    for (int n = 0; n < 4; ++n) {
#pragma unroll
      for (int m = 0; m < 2; ++m) {
#pragma unroll
        for (int r = 0; r < 4; ++r) {
          const float s = acc[m][n][r];
          const int lc = (r == 0) ? lcv[m].x : (r == 1) ? lcv[m].y
                        : (r == 2) ? lcv[m].z : lcv[m].w;
          const float x = (lr[n] == lc) ? -INFINITY : s;   // excl. pos + diag
          nmaxA[n] = fmaxf(nmaxA[n], x);
          const float e = exp2f(fmaf(x, 72.13475205f, -36.06737602f));  // exp(50(x-.5))
          anA[n] += e;                                      // 0 when excluded
          hnA[n] += (x > thrn[n]) ? e : 0.f;                // false when excluded
        }
      }
    }
    cur ^= 1;
  }

  // combine across the 4 g-groups, then one atomic per lane role
#pragma unroll
  for (int n = 0; n < 4; ++n) {
    const int grow = rowBase + n * 16 + l15;
    float nm = nmaxA[n], a0 = anA[n], a1 = hnA[n];
    nm = fmaxf(nm, __shfl_xor(nm, 16)); nm = fmaxf(nm, __shfl_xor(nm, 32));
    a0 += __shfl_xor(a0, 16); a0 += __shfl_xor(a0, 32);
    a1 += __shfl_xor(a1, 16); a1 += __shfl_xor(a1, 32);
    if (g == 0 && nm > -INFINITY) atomicMax(&nmaxu[grow], f2u_mono(nm));
    if (g == 1 && a0 > 0.f) atomicAdd(&anb[grow], a0);
    if (g == 2 && a1 > 0.f) atomicAdd(&hnb[grow], a1);
  }
}

// Fused hard-pos + final reduction (proven): 32 blocks, thread per row.
__global__ __launch_bounds__(256) void k_final(
    const int* __restrict__ rcnt, const unsigned* __restrict__ nmaxu,
    const float* __restrict__ pcache, const float* __restrict__ apb,
    const float* __restrict__ anb, const float* __restrict__ hnb,
    unsigned* __restrict__ done_partial, float* __restrict__ out) {
  unsigned* done = done_partial;
  float* partial = (float*)(done_partial + 1);
  const int t = threadIdx.x;
  const int row = blockIdx.x * 256 + t;
  const int cnt = min(rcnt[row], CAP);
  const float thrp = u2f_mono(nmaxu[row]) + 0.1f;  // sentinel 0 -> NaN -> hp=0
  float hp = 0.f;
  for (int j = 0; j < cnt; ++j) {
    const float p = pcache[(size_t)row * CAP + j];  // +INF diag -> compare false
    hp += (p < thrp) ? exp2f(fmaf(p, -2.885390082f, 1.442695041f)) : 0.f;
  }
  const float ap = apb[row], an = anb[row], hn = hnb[row];
  const bool valid = (ap > 0.f) && (an > 0.f);
  const float ps = (hp > 0.f) ? hp : ap;   // fallback: no hard pos -> all pos
  const float ns = (hn > 0.f) ? hn : an;   // fallback: no hard neg -> all neg
  float acc = valid ? (0.5f * log1pf(ps) + 0.02f * log1pf(ns)) : 0.f;
  float cntv = valid ? 1.f : 0.f;
#pragma unroll
  for (int o = 32; o > 0; o >>= 1) {
    acc += __shfl_down(acc, o);
    cntv += __shfl_down(cntv, o);
  }
  __shared__ float sa[4], sc[4];
  const int w = t >> 6, lane = t & 63;
  if (lane == 0) { sa[w] = acc; sc[w] = cntv; }
  __syncthreads();
  if (t == 0) {
    atomicAdd(&partial[0], sa[0] + sa[1] + sa[2] + sa[3]);
    atomicAdd(&partial[1], sc[0] + sc[1] + sc[2] + sc[3]);
    __threadfence();
    if (atomicAdd(done, 1u) == (unsigned)(NROW / 256 - 1)) {  // last block
      const float A = atomicAdd(&partial[0], 0.f);   // atomic read (coherent)
      const float C = atomicAdd(&partial[1], 0.f);
      out[0] = A / fmaxf(C, 1.f);
    }
  }
}

extern "C" void kernel_launch(void* const* d_in, const int* in_sizes, int n_in,
                              void* d_out, int out_size, void* d_ws, size_t ws_size,
                              hipStream_t stream) {
  const float* emb = (const float*)d_in[0];
  const int* labels = (const int*)d_in[1];
  float* out = (float*)d_out;

  // ws: [embh 2MB][pmin|apb|nmaxu|anb|hnb|rcnt 6x32KB][done+partial 16B][pcache 2MB]
  unsigned short* embh = (unsigned short*)d_ws;
  float* pmin = (float*)((char*)d_ws + (size_t)NROW * NDIM * 2);
  float* apb = pmin + NROW;
  unsigned* nmaxu = (unsigned*)(apb + NROW);
  float* anb = (float*)(nmaxu + NROW);
  float* hnb = anb + NROW;
  int* rcnt = (int*)(hnb + NROW);
  unsigned* done_partial = (unsigned*)(rcnt + NROW);
  float* pcache = (float*)(done_partial + 4);

  k_pre<<<NCLS, 256, 0, stream>>>(emb, labels, embh, nmaxu, anb, hnb,
                                  pmin, apb, rcnt, pcache, done_partial);
  dim3 grid(NROW / (CTILE * NTILE), NROW / RWAVE);  // (16, 128) one-wave blocks
  k_neg<<<grid, 64, 0, stream>>>(embh, labels, pmin, nmaxu, anb, hnb);
  k_final<<<NROW / 256, 256, 0, stream>>>(rcnt, nmaxu, pcache,
                                          apb, anb, hnb, done_partial, out);
}